// Round 6
// baseline (260.288 us; speedup 1.0000x reference)
//
#include <hip/hip_runtime.h>
#include <hip/hip_bf16.h>
#include <hip/hip_fp16.h>

#define N_NODES 50000
#define N_EDGES 800000
#define DIM 128

#define NBUCK 391      // ceil(N/128) buckets of 128 consecutive dst nodes
#define BCAP  2816     // per-bucket staging capacity (mean 2046, sigma 45 -> +17 sigma)
#define CHUNK 2048     // edges per partition block (391 blocks)
#define BSLACK 384     // per-bucket perm4 padding slack (128 nodes * 3 max pad)

#define CVT_BLOCKS 12500   // 12500*256*2 == N_NODES*DIM exactly (2 elems/thread)

typedef float floatx4 __attribute__((ext_vector_type(4)));
typedef float floatx2 __attribute__((ext_vector_type(2)));
typedef short shortx8 __attribute__((ext_vector_type(8)));

__device__ __forceinline__ unsigned short f2bf(float f) {
    union { float f; unsigned int u; } c; c.f = f;
    unsigned int u = c.u;
    unsigned int r = (u + 0x7FFFu + ((u >> 16) & 1u)) >> 16;
    return (unsigned short)r;
}
__device__ __forceinline__ unsigned char f2fp8(float f) {
    unsigned int p = __builtin_amdgcn_cvt_pk_fp8_f32(f, f, 0u, false);
    return (unsigned char)(p & 0xFFu);
}

// ---------------------------------------------------------------------------
// prep: fused  x->bf16 + fp8 HALF-TABLE convert | zero bcursor | weight pack
// fp8 features live in two contiguous [N][64] tables so that one half-dim
// gather pass touches only 3.2 MB (< 4 MiB per-XCD L2).
__global__ __launch_bounds__(256)
void prep_kernel(const float* __restrict__ x, unsigned short* __restrict__ X,
                 unsigned char* __restrict__ X8a, unsigned char* __restrict__ X8b,
                 const float* __restrict__ wr0, const float* __restrict__ wt0,
                 const float* __restrict__ wr1, const float* __restrict__ wt1,
                 const float* __restrict__ wr2, const float* __restrict__ wt2,
                 unsigned short* __restrict__ Wp, int* __restrict__ bcursor) {
    int b = blockIdx.x;
    if (b < CVT_BLOCKS) {
        int i = (b * 256 + threadIdx.x) * 2;   // N*DIM exact multiple of 512
        float2 xv = *(const float2*)(x + i);
        *(unsigned int*)(X + i) =
            (unsigned int)f2bf(xv.x) | ((unsigned int)f2bf(xv.y) << 16);
        unsigned int p8 = __builtin_amdgcn_cvt_pk_fp8_f32(xv.x, xv.y, 0u, false);
        int node = i >> 7, d = i & 127;        // d is even, pair never straddles 64
        unsigned char* t = (d < 64) ? X8a : X8b;
        *(unsigned short*)(t + (size_t)node * 64 + (d & 63)) = (unsigned short)(p8 & 0xFFFFu);
    } else if (b == CVT_BLOCKS) {
        for (int i = threadIdx.x; i < NBUCK; i += 256) bcursor[i] = 0;
    } else {
        int id = (b - CVT_BLOCKS - 1) * 256 + threadIdx.x;   // < 3*32768
        int layer = id >> 15;
        int rem = id & 32767;
        int j  = rem & 7;
        int L  = (rem >> 3) & 63;
        int ct = (rem >> 9) & 7;
        int t  = rem >> 12;
        int k = t * 32 + (L >> 4) * 8 + j;
        int c = ct * 16 + (L & 15);
        const float* wr = (layer == 0) ? wr0 : (layer == 1) ? wr1 : wr2;
        const float* wt = (layer == 0) ? wt0 : (layer == 1) ? wt1 : wt2;
        float v = (k < 128) ? wr[k * 128 + c] : wt[(k - 128) * 128 + c];
        Wp[id] = f2bf(v);
    }
}

// Pass 1: bin edges by bucket (dst>>7) through LDS, contiguous runs to staging.
__global__ __launch_bounds__(1024)
void partition_kernel(const int* __restrict__ src, const int* __restrict__ dst,
                      const float* __restrict__ ew,
                      int* __restrict__ bcursor, int2* __restrict__ bstage, int e) {
    __shared__ int2 stage[CHUNK];      // 16 KB
    __shared__ int cnt[NBUCK];
    __shared__ int lbase[NBUCK];
    __shared__ int gbase[NBUCK];
    __shared__ int wsum[16];
    const int tid = threadIdx.x;
    const int e0 = blockIdx.x * CHUNK;
    const int ecnt = min(CHUNK, e - e0);

    for (int i = tid; i < NBUCK; i += 1024) cnt[i] = 0;
    __syncthreads();
    for (int i = tid; i < ecnt; i += 1024)
        atomicAdd(&cnt[dst[e0 + i] >> 7], 1);
    __syncthreads();

    {
        int v = (tid < NBUCK) ? cnt[tid] : 0;
        int lane = tid & 63, wid = tid >> 6;
        int acc = v;
#pragma unroll
        for (int off = 1; off < 64; off <<= 1) {
            int t = __shfl_up(acc, off, 64);
            if (lane >= off) acc += t;
        }
        if (lane == 63) wsum[wid] = acc;
        __syncthreads();
        int wpref = 0;
        for (int w = 0; w < wid; ++w) wpref += wsum[w];
        int excl = wpref + acc - v;
        if (tid < NBUCK) {
            lbase[tid] = excl;
            gbase[tid] = atomicAdd(&bcursor[tid], v);
            cnt[tid] = 0;            // reuse as local cursor
        }
    }
    __syncthreads();

    for (int i = tid; i < ecnt; i += 1024) {
        int d = dst[e0 + i];
        int s = src[e0 + i];
        unsigned int hw = (unsigned int)__half_as_ushort(__float2half(ew[e0 + i]));
        int b = d >> 7;
        int pos = atomicAdd(&cnt[b], 1);
        stage[lbase[b] + pos] = make_int2((int)((hw << 16) | (unsigned int)s), d);
    }
    __syncthreads();

    for (int j = tid; j < ecnt; j += 1024) {
        int2 p = stage[j];
        int b = p.y >> 7;
        int gidx = b * BCAP + gbase[b] + (j - lbase[b]);
        bstage[gidx] = p;
    }
}

// Pass 2: per bucket (128 nodes, 391 blocks), 512 threads.
// Per-node lists in perm4 are padded to a multiple of 4 (pad entries = 0:
// src 0, weight +0.0). Bucket b's perm4 window starts at rawScan(b) + b*BSLACK.
__global__ __launch_bounds__(512)
void bucket_fill_kernel(const int2* __restrict__ bstage, const int* __restrict__ bcursor,
                        int* __restrict__ row_start, int* __restrict__ row_end,
                        unsigned int* __restrict__ perm4, int n) {
    __shared__ int cnt128[128];
    __shared__ int curs[128];
    __shared__ int wsum[8];
    __shared__ int sbase, scnt;
    const int tid = threadIdx.x;
    const int b = blockIdx.x;
    const int node0 = b << 7;
    const int lane = tid & 63, wid = tid >> 6;

    // exclusive prefix over 391 raw bucket totals, 1 entry per thread
    {
        int v = (tid < NBUCK) ? bcursor[tid] : 0;
        int acc = v;
#pragma unroll
        for (int off = 1; off < 64; off <<= 1) {
            int t = __shfl_up(acc, off, 64);
            if (lane >= off) acc += t;
        }
        if (lane == 63) wsum[wid] = acc;
        __syncthreads();
        int wpref = 0;
        for (int w = 0; w < wid; ++w) wpref += wsum[w];
        int excl = wpref + acc - v;
        if (tid == b) { sbase = excl; scnt = v; }
    }
    __syncthreads();
    const int cntb = scnt;
    const int base = sbase + b * BSLACK;     // padded slack per bucket
    const int2* sp = bstage + (size_t)b * BCAP;

    if (tid < 128) cnt128[tid] = 0;
    __syncthreads();
    for (int i = tid; i < cntb; i += 512)
        atomicAdd(&cnt128[sp[i].y & 127], 1);
    __syncthreads();

    // scan 128 per-node PADDED counts (first 2 waves carry data)
    int v = (tid < 128) ? cnt128[tid] : 0;
    int pcv = (v + 3) & ~3;
    int acc = pcv;
#pragma unroll
    for (int off = 1; off < 64; off <<= 1) {
        int t = __shfl_up(acc, off, 64);
        if (lane >= off) acc += t;
    }
    if (lane == 63) wsum[wid] = acc;
    __syncthreads();
    int wpref = 0;
    for (int w = 0; w < wid; ++w) wpref += wsum[w];
    int excl = wpref + acc - pcv;
    if (tid < 128) {
        int node = node0 + tid;
        if (node < n) {
            row_start[node] = base + excl;
            row_end[node]   = base + excl + pcv;
        }
        curs[tid] = excl;
        // zero-fill the <=3 pad slots so they read as (src 0, weight +0.0)
        for (int k = v; k < pcv; ++k) perm4[base + excl + k] = 0u;
    }
    __syncthreads();

    for (int i = tid; i < cntb; i += 512) {
        int2 p = sp[i];
        int pos = atomicAdd(&curs[p.y & 127], 1);
        perm4[base + pos] = (unsigned int)p.x;
    }
}

// ---------------------------------------------------------------------------
// Aggregation, one 64-dim HALF per launch. The gathered table (t8, [N][64]
// fp8 = 3.2 MB) fits in every XCD's 4 MiB L2, so steady-state gathers are
// L2 hits. Lane-group g (16 lanes) owns node nodeBase+g; lane sl covers
// dims [4sl, 4sl+4) of the half (one dword gather per edge per lane).
// Guard-free quad loop (perm lists padded to x4), 2-deep pipeline.
#define ACC2(p, v) do { \
    float w_ = __half2float(__ushort_as_half((unsigned short)((p) >> 16))); \
    floatx2 W_ = (floatx2){w_, w_}; \
    ac0 += W_ * __builtin_amdgcn_cvt_pk_f32_fp8((v), false); \
    ac1 += W_ * __builtin_amdgcn_cvt_pk_f32_fp8((v), true);  \
} while (0)

__global__ __launch_bounds__(256, 8)
void agg_half_kernel(const unsigned char* __restrict__ t8,
                     const int* __restrict__ row_start, const int* __restrict__ row_end,
                     const unsigned int* __restrict__ perm4,
                     unsigned short* __restrict__ aggOut) {   // = Agg + 64*half
    const int tid  = threadIdx.x;
    const int lane = tid & 63;
    const int wid  = tid >> 6;
    const int g  = lane >> 4;
    const int sl = lane & 15;
    const int nodeBase = blockIdx.x * 16 + wid * 4;

    int rs = 0;
    {
        int idx = nodeBase + (lane & 3);
        if (lane < 4)      rs = row_start[idx];
        else if (lane < 8) rs = row_end[idx];
    }
    const int beg = __shfl(rs, g, 64);
    const int end = __shfl(rs, g + 4, 64);

    floatx2 ac0 = (floatx2){0.f, 0.f}, ac1 = (floatx2){0.f, 0.f};
    const unsigned char* hp = t8 + sl * 4;
    const bool any = beg < end;
    uint4 P = {};
    unsigned int v0 = 0, v1 = 0, v2 = 0, v3 = 0;
    int t = beg;
    if (any) {
        P  = *(const uint4*)(perm4 + t);     // 16B broadcast, beg is x4-aligned
        v0 = *(const unsigned int*)(hp + (size_t)(P.x & 0xFFFFu) * 64);
        v1 = *(const unsigned int*)(hp + (size_t)(P.y & 0xFFFFu) * 64);
        v2 = *(const unsigned int*)(hp + (size_t)(P.z & 0xFFFFu) * 64);
        v3 = *(const unsigned int*)(hp + (size_t)(P.w & 0xFFFFu) * 64);
    }
    for (; t + 4 < end; t += 4) {
        uint4 Pn = *(const uint4*)(perm4 + t + 4);
        unsigned int w0 = *(const unsigned int*)(hp + (size_t)(Pn.x & 0xFFFFu) * 64);
        unsigned int w1 = *(const unsigned int*)(hp + (size_t)(Pn.y & 0xFFFFu) * 64);
        unsigned int w2 = *(const unsigned int*)(hp + (size_t)(Pn.z & 0xFFFFu) * 64);
        unsigned int w3 = *(const unsigned int*)(hp + (size_t)(Pn.w & 0xFFFFu) * 64);
        ACC2(P.x, v0); ACC2(P.y, v1); ACC2(P.z, v2); ACC2(P.w, v3);
        P = Pn;
        v0 = w0; v1 = w1; v2 = w2; v3 = w3;
    }
    if (any) { ACC2(P.x, v0); ACC2(P.y, v1); ACC2(P.z, v2); ACC2(P.w, v3); }

    uint2 r;
    r.x = (unsigned int)f2bf(ac0.x) | ((unsigned int)f2bf(ac0.y) << 16);
    r.y = (unsigned int)f2bf(ac1.x) | ((unsigned int)f2bf(ac1.y) << 16);
    *(uint2*)(aggOut + (size_t)(nodeBase + g) * DIM + sl * 4) = r;
}

// ---------------------------------------------------------------------------
// GEMM per layer: out = [Agg | h] . Wp + bias. No LDS, no barrier — A-frags
// stream from global (Agg rows were written by the same-ordinal agg block ->
// same XCD L2; h rows by the same-ordinal gemm block of the previous layer).
__global__ __launch_bounds__(256, 4)
void gemm_layer(const unsigned short* __restrict__ h, const unsigned short* __restrict__ agg,
                const unsigned short* __restrict__ Wp, const float* __restrict__ bias,
                float* __restrict__ outF, unsigned short* __restrict__ outB,
                unsigned char* __restrict__ o8a, unsigned char* __restrict__ o8b,
                int relu) {
    const int tid  = threadIdx.x;
    const int lane = tid & 63;
    const int wid  = tid >> 6;
    const int g  = lane >> 4;
    const int sl = lane & 15;
    const int rowT = blockIdx.x * 16;
    const int rr = rowT + sl;          // grid exact: always < N
    const int ko = g * 8;

    floatx4 acc2[2];
#pragma unroll
    for (int ct = 0; ct < 2; ++ct) acc2[ct] = (floatx4){0.f, 0.f, 0.f, 0.f};

#pragma unroll
    for (int t2 = 0; t2 < 8; ++t2) {
        const unsigned short* ap = (t2 < 4)
            ? (agg + (size_t)rr * DIM + t2 * 32 + ko)
            : (h   + (size_t)rr * DIM + (t2 - 4) * 32 + ko);
        shortx8 a = *(const shortx8*)ap;
        const unsigned short* wp = Wp + (size_t)t2 * 4096 + (wid * 2) * 512 + lane * 8;
#pragma unroll
        for (int ct = 0; ct < 2; ++ct) {
            shortx8 b = *(const shortx8*)(wp + ct * 512);
            acc2[ct] = __builtin_amdgcn_mfma_f32_16x16x32_bf16(a, b, acc2[ct], 0, 0, 0);
        }
    }

#pragma unroll
    for (int ct = 0; ct < 2; ++ct) {
        int col = wid * 32 + ct * 16 + sl;
        float bv = bias[col];
#pragma unroll
        for (int i = 0; i < 4; ++i) {
            int row = rowT + g * 4 + i;
            float v = acc2[ct][i] + bv;
            if (relu) v = fmaxf(v, 0.f);
            if (outF) {
                outF[(size_t)row * DIM + col] = v;
            } else {
                outB[(size_t)row * DIM + col] = f2bf(v);
                unsigned char* t = (col < 64) ? o8a : o8b;
                t[(size_t)row * 64 + (col & 63)] = f2fp8(v);
            }
        }
    }
}

extern "C" void kernel_launch(void* const* d_in, const int* in_sizes, int n_in,
                              void* d_out, int out_size, void* d_ws, size_t ws_size,
                              hipStream_t stream) {
    const int N = N_NODES, E = N_EDGES;

    const float* x   = (const float*)d_in[0];
    const int*   ei  = (const int*)d_in[1];
    const float* ea  = (const float*)d_in[2];
    const float* wr0 = (const float*)d_in[3];
    const float* br0 = (const float*)d_in[4];
    const float* wt0 = (const float*)d_in[5];
    const float* wr1 = (const float*)d_in[6];
    const float* br1 = (const float*)d_in[7];
    const float* wt1 = (const float*)d_in[8];
    const float* wr2 = (const float*)d_in[9];
    const float* br2 = (const float*)d_in[10];
    const float* wt2 = (const float*)d_in[11];
    const int* srcI = ei;
    const int* dstI = ei + E;
    float* out = (float*)d_out;

    // workspace layout — every array size is a multiple of 128 B, so the fp8
    // half-tables (3.2 MB each), Agg and perm4 are all 128B-aligned.
    int2* bstage = (int2*)d_ws;                              // 8,808,448 B
    unsigned short* X  = (unsigned short*)(bstage + (size_t)NBUCK * BCAP);  // 12.8 MB
    unsigned short* H1 = X + (size_t)N * DIM;                // 12.8 MB
    unsigned short* H2 = H1 + (size_t)N * DIM;               // 12.8 MB
    unsigned short* Wp = H2 + (size_t)N * DIM;               // 196,608 B
    unsigned char* X8a  = (unsigned char*)(Wp + 3 * 32768);  // 6 half-tables, 3.2 MB each
    unsigned char* X8b  = X8a  + (size_t)N * 64;
    unsigned char* H81a = X8b  + (size_t)N * 64;
    unsigned char* H81b = H81a + (size_t)N * 64;
    unsigned char* H82a = H81b + (size_t)N * 64;
    unsigned char* H82b = H82a + (size_t)N * 64;
    unsigned short* Agg = (unsigned short*)(H82b + (size_t)N * 64);  // N*128 bf16 = 12.8 MB
    unsigned int* perm4 = (unsigned int*)(Agg + (size_t)N * DIM);    // E + pad < 1M u32
    int* bcursor = (int*)(perm4 + 1000000);                  // NBUCK i32
    int* rowst   = bcursor + NBUCK;                          // N i32
    int* rowend  = rowst + N_NODES;                          // N i32

    // prep (cvt + zero + pack) and CSR build via binned counting sort
    prep_kernel<<<CVT_BLOCKS + 1 + 384, 256, 0, stream>>>(x, X, X8a, X8b, wr0, wt0, wr1, wt1, wr2, wt2, Wp, bcursor);
    partition_kernel<<<(E + CHUNK - 1) / CHUNK, 1024, 0, stream>>>(srcI, dstI, ea, bcursor, bstage, E);
    bucket_fill_kernel<<<NBUCK, 512, 0, stream>>>(bstage, bcursor, rowst, rowend, perm4, N);

    const int G = N / 16;                    // 3125 blocks, 16 nodes each (exact)

    // layer 0
    agg_half_kernel<<<G, 256, 0, stream>>>(X8a, rowst, rowend, perm4, Agg);
    agg_half_kernel<<<G, 256, 0, stream>>>(X8b, rowst, rowend, perm4, Agg + 64);
    gemm_layer<<<G, 256, 0, stream>>>(X, Agg, Wp, br0, nullptr, H1, H81a, H81b, 1);
    // layer 1
    agg_half_kernel<<<G, 256, 0, stream>>>(H81a, rowst, rowend, perm4, Agg);
    agg_half_kernel<<<G, 256, 0, stream>>>(H81b, rowst, rowend, perm4, Agg + 64);
    gemm_layer<<<G, 256, 0, stream>>>(H1, Agg, Wp + 32768, br1, nullptr, H2, H82a, H82b, 1);
    // layer 2
    agg_half_kernel<<<G, 256, 0, stream>>>(H82a, rowst, rowend, perm4, Agg);
    agg_half_kernel<<<G, 256, 0, stream>>>(H82b, rowst, rowend, perm4, Agg + 64);
    gemm_layer<<<G, 256, 0, stream>>>(H2, Agg, Wp + 65536, br2, out, nullptr, nullptr, nullptr, 0);
}

// Round 8
// 253.864 us; speedup vs baseline: 1.0253x; 1.0253x over previous
//
#include <hip/hip_runtime.h>
#include <hip/hip_bf16.h>
#include <hip/hip_fp16.h>

#define N_NODES 50000
#define N_EDGES 800000
#define DIM 128

#define NBUCK 391      // ceil(N/128) buckets of 128 consecutive dst nodes
#define BCAP  2816     // per-bucket staging capacity (mean 2046, sigma 45 -> +17 sigma)
#define CHUNK 2048     // edges per partition block (391 blocks)
#define BSLACK 384     // per-bucket perm4 padding slack (128 nodes * 3 max pad)

#define CVT_BLOCKS 12500   // 12500*256*2 == N_NODES*DIM exactly (2 elems/thread)

#define LDSROW 136     // Gs row stride in shorts (272 B: 2-way bank alias = free)

typedef float floatx4 __attribute__((ext_vector_type(4)));
typedef float floatx2 __attribute__((ext_vector_type(2)));
typedef short shortx8 __attribute__((ext_vector_type(8)));
typedef unsigned int uintx4 __attribute__((ext_vector_type(4)));   // nontemporal-capable

__device__ __forceinline__ unsigned short f2bf(float f) {
    union { float f; unsigned int u; } c; c.f = f;
    unsigned int u = c.u;
    unsigned int r = (u + 0x7FFFu + ((u >> 16) & 1u)) >> 16;
    return (unsigned short)r;
}
__device__ __forceinline__ unsigned char f2fp8(float f) {
    unsigned int p = __builtin_amdgcn_cvt_pk_fp8_f32(f, f, 0u, false);
    return (unsigned char)(p & 0xFFu);
}

// ---------------------------------------------------------------------------
// prep: fused  x->bf16+fp8 convert | zero bcursor | weight pack
__global__ __launch_bounds__(256)
void prep_kernel(const float* __restrict__ x, unsigned short* __restrict__ X,
                 unsigned char* __restrict__ X8,
                 const float* __restrict__ wr0, const float* __restrict__ wt0,
                 const float* __restrict__ wr1, const float* __restrict__ wt1,
                 const float* __restrict__ wr2, const float* __restrict__ wt2,
                 unsigned short* __restrict__ Wp, int* __restrict__ bcursor) {
    int b = blockIdx.x;
    if (b < CVT_BLOCKS) {
        int i = (b * 256 + threadIdx.x) * 2;   // N*DIM exact multiple of 512
        float2 xv = *(const float2*)(x + i);
        *(unsigned int*)(X + i) =
            (unsigned int)f2bf(xv.x) | ((unsigned int)f2bf(xv.y) << 16);
        unsigned int p8 = __builtin_amdgcn_cvt_pk_fp8_f32(xv.x, xv.y, 0u, false);
        *(unsigned short*)(X8 + i) = (unsigned short)(p8 & 0xFFFFu);
    } else if (b == CVT_BLOCKS) {
        for (int i = threadIdx.x; i < NBUCK; i += 256) bcursor[i] = 0;
    } else {
        int id = (b - CVT_BLOCKS - 1) * 256 + threadIdx.x;   // < 3*32768
        int layer = id >> 15;
        int rem = id & 32767;
        int j  = rem & 7;
        int L  = (rem >> 3) & 63;
        int ct = (rem >> 9) & 7;
        int t  = rem >> 12;
        int k = t * 32 + (L >> 4) * 8 + j;
        int c = ct * 16 + (L & 15);
        const float* wr = (layer == 0) ? wr0 : (layer == 1) ? wr1 : wr2;
        const float* wt = (layer == 0) ? wt0 : (layer == 1) ? wt1 : wt2;
        float v = (k < 128) ? wr[k * 128 + c] : wt[(k - 128) * 128 + c];
        Wp[id] = f2bf(v);
    }
}

// Pass 1: bin edges by bucket (dst>>7) through LDS, contiguous runs to staging.
__global__ __launch_bounds__(1024)
void partition_kernel(const int* __restrict__ src, const int* __restrict__ dst,
                      const float* __restrict__ ew,
                      int* __restrict__ bcursor, int2* __restrict__ bstage, int e) {
    __shared__ int2 stage[CHUNK];      // 16 KB
    __shared__ int cnt[NBUCK];
    __shared__ int lbase[NBUCK];
    __shared__ int gbase[NBUCK];
    __shared__ int wsum[16];
    const int tid = threadIdx.x;
    const int e0 = blockIdx.x * CHUNK;
    const int ecnt = min(CHUNK, e - e0);

    for (int i = tid; i < NBUCK; i += 1024) cnt[i] = 0;
    __syncthreads();
    for (int i = tid; i < ecnt; i += 1024)
        atomicAdd(&cnt[dst[e0 + i] >> 7], 1);
    __syncthreads();

    {
        int v = (tid < NBUCK) ? cnt[tid] : 0;
        int lane = tid & 63, wid = tid >> 6;
        int acc = v;
#pragma unroll
        for (int off = 1; off < 64; off <<= 1) {
            int t = __shfl_up(acc, off, 64);
            if (lane >= off) acc += t;
        }
        if (lane == 63) wsum[wid] = acc;
        __syncthreads();
        int wpref = 0;
        for (int w = 0; w < wid; ++w) wpref += wsum[w];
        int excl = wpref + acc - v;
        if (tid < NBUCK) {
            lbase[tid] = excl;
            gbase[tid] = atomicAdd(&bcursor[tid], v);
            cnt[tid] = 0;            // reuse as local cursor
        }
    }
    __syncthreads();

    for (int i = tid; i < ecnt; i += 1024) {
        int d = dst[e0 + i];
        int s = src[e0 + i];
        unsigned int hw = (unsigned int)__half_as_ushort(__float2half(ew[e0 + i]));
        int b = d >> 7;
        int pos = atomicAdd(&cnt[b], 1);
        stage[lbase[b] + pos] = make_int2((int)((hw << 16) | (unsigned int)s), d);
    }
    __syncthreads();

    for (int j = tid; j < ecnt; j += 1024) {
        int2 p = stage[j];
        int b = p.y >> 7;
        int gidx = b * BCAP + gbase[b] + (j - lbase[b]);
        bstage[gidx] = p;
    }
}

// Pass 2: per bucket (128 nodes, 391 blocks), 512 threads.
// Per-node lists in perm4 are padded to a multiple of 4 (pad entries = 0:
// src 0, weight +0.0). Bucket b's perm4 window starts at rawScan(b) + b*BSLACK.
// row_start/row_end give each node's padded [beg,end).
__global__ __launch_bounds__(512)
void bucket_fill_kernel(const int2* __restrict__ bstage, const int* __restrict__ bcursor,
                        int* __restrict__ row_start, int* __restrict__ row_end,
                        unsigned int* __restrict__ perm4, int n) {
    __shared__ int cnt128[128];
    __shared__ int curs[128];
    __shared__ int wsum[8];
    __shared__ int sbase, scnt;
    const int tid = threadIdx.x;
    const int b = blockIdx.x;
    const int node0 = b << 7;
    const int lane = tid & 63, wid = tid >> 6;

    // exclusive prefix over 391 raw bucket totals, 1 entry per thread
    {
        int v = (tid < NBUCK) ? bcursor[tid] : 0;
        int acc = v;
#pragma unroll
        for (int off = 1; off < 64; off <<= 1) {
            int t = __shfl_up(acc, off, 64);
            if (lane >= off) acc += t;
        }
        if (lane == 63) wsum[wid] = acc;
        __syncthreads();
        int wpref = 0;
        for (int w = 0; w < wid; ++w) wpref += wsum[w];
        int excl = wpref + acc - v;
        if (tid == b) { sbase = excl; scnt = v; }
    }
    __syncthreads();
    const int cntb = scnt;
    const int base = sbase + b * BSLACK;     // padded slack per bucket
    const int2* sp = bstage + (size_t)b * BCAP;

    if (tid < 128) cnt128[tid] = 0;
    __syncthreads();
    for (int i = tid; i < cntb; i += 512)
        atomicAdd(&cnt128[sp[i].y & 127], 1);
    __syncthreads();

    // scan 128 per-node PADDED counts (first 2 waves carry data)
    int v = (tid < 128) ? cnt128[tid] : 0;
    int pcv = (v + 3) & ~3;
    int acc = pcv;
#pragma unroll
    for (int off = 1; off < 64; off <<= 1) {
        int t = __shfl_up(acc, off, 64);
        if (lane >= off) acc += t;
    }
    if (lane == 63) wsum[wid] = acc;
    __syncthreads();
    int wpref = 0;
    for (int w = 0; w < wid; ++w) wpref += wsum[w];
    int excl = wpref + acc - pcv;
    if (tid < 128) {
        int node = node0 + tid;
        if (node < n) {
            row_start[node] = base + excl;
            row_end[node]   = base + excl + pcv;
        }
        curs[tid] = excl;
        // zero-fill the <=3 pad slots so they read as (src 0, weight +0.0)
        for (int k = v; k < pcv; ++k) perm4[base + excl + k] = 0u;
    }
    __syncthreads();

    for (int i = tid; i < cntb; i += 512) {
        int2 p = sp[i];
        int pos = atomicAdd(&curs[p.y & 127], 1);
        perm4[base + pos] = (unsigned int)p.x;
    }
}

// ---------------------------------------------------------------------------
// Fused layer v10 = v9 + NON-TEMPORAL streams. Touch-once traffic (perm4
// quads, root-path h rows, all output stores) is marked nt so it does not
// evict the 6.4 MB fp8 gather table from the per-XCD L2. Gather loads of the
// table stay cacheable. Structure and numerics identical to v9.
#define ACCQ(p, v) do { \
    float w_ = __half2float(__ushort_as_half((unsigned short)((p) >> 16))); \
    floatx2 W_ = (floatx2){w_, w_}; \
    floatx2 f0_ = __builtin_amdgcn_cvt_pk_f32_fp8((v).x, false); \
    floatx2 f1_ = __builtin_amdgcn_cvt_pk_f32_fp8((v).x, true);  \
    floatx2 f2_ = __builtin_amdgcn_cvt_pk_f32_fp8((v).y, false); \
    floatx2 f3_ = __builtin_amdgcn_cvt_pk_f32_fp8((v).y, true);  \
    ac[0] += W_ * f0_; ac[1] += W_ * f1_; \
    ac[2] += W_ * f2_; ac[3] += W_ * f3_; \
} while (0)

__global__ __launch_bounds__(256, 6)
void fused_layer(const unsigned short* __restrict__ h, const unsigned char* __restrict__ h8,
                 const int* __restrict__ row_start, const int* __restrict__ row_end,
                 const unsigned int* __restrict__ perm4, const unsigned short* __restrict__ Wp,
                 const float* __restrict__ bias, float* __restrict__ outF,
                 unsigned short* __restrict__ outB, unsigned char* __restrict__ outB8,
                 int relu) {
    __shared__ unsigned short Gs[16 * LDSROW];   // 4.25 KB
    const int tid  = threadIdx.x;
    const int lane = tid & 63;
    const int wid  = tid >> 6;
    const int g  = lane >> 4;      // node owner (phase1) / k-offset quad (phase2)
    const int sl = lane & 15;      // col-chunk (phase1) / A-row (phase2)
    const int rowT = blockIdx.x * 16;
    const int nodeBase = rowT + wid * 4;

    // beg/end for the wave's 4 nodes: lanes 0-3 load row_start, 4-7 row_end
    int rs = 0;
    {
        int idx = nodeBase + (lane & 3);
        if (lane < 4)      rs = row_start[idx];
        else if (lane < 8) rs = row_end[idx];
    }
    const int beg = __shfl(rs, g, 64);
    const int end = __shfl(rs, g + 4, 64);

    // ---- phase 1: group g aggregates node nodeBase+g, dims [8sl, 8sl+8) ----
    floatx2 ac[4];
#pragma unroll
    for (int k = 0; k < 4; ++k) ac[k] = (floatx2){0.f, 0.f};
    const unsigned char* hp8 = h8 + sl * 8;
    const bool any = beg < end;
    uintx4 P = {};
    uint2 v0 = {}, v1 = {}, v2 = {}, v3 = {};
    int t = beg;
    if (any) {
        P  = __builtin_nontemporal_load((const uintx4*)(perm4 + t));  // 16B bcast
        v0 = *(const uint2*)(hp8 + (size_t)(P.x & 0xFFFFu) * DIM);
        v1 = *(const uint2*)(hp8 + (size_t)(P.y & 0xFFFFu) * DIM);
        v2 = *(const uint2*)(hp8 + (size_t)(P.z & 0xFFFFu) * DIM);
        v3 = *(const uint2*)(hp8 + (size_t)(P.w & 0xFFFFu) * DIM);
    }
    for (; t + 4 < end; t += 4) {
        uintx4 Pn = __builtin_nontemporal_load((const uintx4*)(perm4 + t + 4));
        uint2 w0 = *(const uint2*)(hp8 + (size_t)(Pn.x & 0xFFFFu) * DIM);
        uint2 w1 = *(const uint2*)(hp8 + (size_t)(Pn.y & 0xFFFFu) * DIM);
        uint2 w2 = *(const uint2*)(hp8 + (size_t)(Pn.z & 0xFFFFu) * DIM);
        uint2 w3 = *(const uint2*)(hp8 + (size_t)(Pn.w & 0xFFFFu) * DIM);
        ACCQ(P.x, v0); ACCQ(P.y, v1); ACCQ(P.z, v2); ACCQ(P.w, v3);
        P = Pn;
        v0 = w0; v1 = w1; v2 = w2; v3 = w3;
    }
    if (any) { ACCQ(P.x, v0); ACCQ(P.y, v1); ACCQ(P.z, v2); ACCQ(P.w, v3); }

    // group g's 16 lanes hold the full 128-dim aggregate of its node
    {
        uint4 r;
        r.x = (unsigned int)f2bf(ac[0].x) | ((unsigned int)f2bf(ac[0].y) << 16);
        r.y = (unsigned int)f2bf(ac[1].x) | ((unsigned int)f2bf(ac[1].y) << 16);
        r.z = (unsigned int)f2bf(ac[2].x) | ((unsigned int)f2bf(ac[2].y) << 16);
        r.w = (unsigned int)f2bf(ac[3].x) | ((unsigned int)f2bf(ac[3].y) << 16);
        *(uint4*)(&Gs[(wid * 4 + g) * LDSROW + sl * 8]) = r;
    }

    // ---- phase 1.5: root-GEMM half (h rows, no LDS dependency) ----
    floatx4 acc2[2];
#pragma unroll
    for (int ct = 0; ct < 2; ++ct) acc2[ct] = (floatx4){0.f, 0.f, 0.f, 0.f};
    const int rr = rowT + sl;          // grid exact: always < N
    const int ko = g * 8;
#pragma unroll
    for (int t2 = 4; t2 < 8; ++t2) {
        shortx8 a = __builtin_nontemporal_load(
            (const shortx8*)(h + (size_t)rr * DIM + (t2 - 4) * 32 + ko));
        const unsigned short* wp = Wp + (size_t)t2 * 4096 + (wid * 2) * 512 + lane * 8;
#pragma unroll
        for (int ct = 0; ct < 2; ++ct) {
            shortx8 b = *(const shortx8*)(wp + ct * 512);
            acc2[ct] = __builtin_amdgcn_mfma_f32_16x16x32_bf16(a, b, acc2[ct], 0, 0, 0);
        }
    }

    __syncthreads();   // waves now read rows written by other waves

    // ---- phase 2: aggregate-GEMM half from LDS ----
#pragma unroll
    for (int t2 = 0; t2 < 4; ++t2) {
        shortx8 a = *(const shortx8*)(&Gs[sl * LDSROW + t2 * 32 + ko]);
        const unsigned short* wp = Wp + (size_t)t2 * 4096 + (wid * 2) * 512 + lane * 8;
#pragma unroll
        for (int ct = 0; ct < 2; ++ct) {
            shortx8 b = *(const shortx8*)(wp + ct * 512);
            acc2[ct] = __builtin_amdgcn_mfma_f32_16x16x32_bf16(a, b, acc2[ct], 0, 0, 0);
        }
    }

#pragma unroll
    for (int ct = 0; ct < 2; ++ct) {
        int col = wid * 32 + ct * 16 + sl;
        float bv = bias[col];
#pragma unroll
        for (int i = 0; i < 4; ++i) {
            int row = rowT + g * 4 + i;
            float v = acc2[ct][i] + bv;
            if (relu) v = fmaxf(v, 0.f);
            if (outF) {
                __builtin_nontemporal_store(v, &outF[(size_t)row * DIM + col]);
            } else {
                __builtin_nontemporal_store(f2bf(v), &outB[(size_t)row * DIM + col]);
                __builtin_nontemporal_store(f2fp8(v), &outB8[(size_t)row * DIM + col]);
            }
        }
    }
}

extern "C" void kernel_launch(void* const* d_in, const int* in_sizes, int n_in,
                              void* d_out, int out_size, void* d_ws, size_t ws_size,
                              hipStream_t stream) {
    const int N = N_NODES, E = N_EDGES;

    const float* x   = (const float*)d_in[0];
    const int*   ei  = (const int*)d_in[1];
    const float* ea  = (const float*)d_in[2];
    const float* wr0 = (const float*)d_in[3];
    const float* br0 = (const float*)d_in[4];
    const float* wt0 = (const float*)d_in[5];
    const float* wr1 = (const float*)d_in[6];
    const float* br1 = (const float*)d_in[7];
    const float* wt1 = (const float*)d_in[8];
    const float* wr2 = (const float*)d_in[9];
    const float* br2 = (const float*)d_in[10];
    const float* wt2 = (const float*)d_in[11];
    const int* srcI = ei;
    const int* dstI = ei + E;
    float* out = (float*)d_out;

    // workspace layout — every array before the fp8 tables has a size that is
    // a multiple of 128 B, so X8/H81/H82 rows are 128B-aligned (2 lines/row),
    // and perm4 is 128B-aligned (dwordx4 quad loads).
    int2* bstage = (int2*)d_ws;                              // 391*2816*8 = 8,808,448 B
    unsigned short* X  = (unsigned short*)(bstage + (size_t)NBUCK * BCAP);  // 12.8 MB
    unsigned short* H1 = X + (size_t)N * DIM;                // 12.8 MB
    unsigned short* H2 = H1 + (size_t)N * DIM;               // 12.8 MB
    unsigned short* Wp = H2 + (size_t)N * DIM;               // 196,608 B
    unsigned char* X8  = (unsigned char*)(Wp + 3 * 32768);   // 6.4 MB (128B-aligned)
    unsigned char* H81 = X8 + (size_t)N * DIM;               // 6.4 MB
    unsigned char* H82 = H81 + (size_t)N * DIM;              // 6.4 MB
    unsigned int* perm4 = (unsigned int*)(H82 + (size_t)N * DIM);  // E + NBUCK*BSLACK (<1M) u32
    int* bcursor = (int*)(perm4 + 1000000);                  // NBUCK i32
    int* rowst   = bcursor + NBUCK;                          // N i32
    int* rowend  = rowst + N_NODES;                          // N i32

    // prep (cvt + zero + pack) and CSR build via binned counting sort
    prep_kernel<<<CVT_BLOCKS + 1 + 384, 256, 0, stream>>>(x, X, X8, wr0, wt0, wr1, wt1, wr2, wt2, Wp, bcursor);
    partition_kernel<<<(E + CHUNK - 1) / CHUNK, 1024, 0, stream>>>(srcI, dstI, ea, bcursor, bstage, E);
    bucket_fill_kernel<<<NBUCK, 512, 0, stream>>>(bstage, bcursor, rowst, rowend, perm4, N);

    const int fusedGrid = N / 16;            // 3125 blocks, 16 rows each (exact)

    // ping-pong h buffers: gathers read prev layer's fp8 copy
    fused_layer<<<fusedGrid, 256, 0, stream>>>(X,  X8,  rowst, rowend, perm4, Wp,         br0, nullptr, H1, H81, 1);
    fused_layer<<<fusedGrid, 256, 0, stream>>>(H1, H81, rowst, rowend, perm4, Wp + 32768, br1, nullptr, H2, H82, 1);
    fused_layer<<<fusedGrid, 256, 0, stream>>>(H2, H82, rowst, rowend, perm4, Wp + 65536, br2, out, nullptr, nullptr, 0);
}

// Round 9
// 232.727 us; speedup vs baseline: 1.1184x; 1.0908x over previous
//
#include <hip/hip_runtime.h>
#include <hip/hip_bf16.h>
#include <hip/hip_fp16.h>

#define N_NODES 50000
#define N_EDGES 800000
#define DIM 128

#define NBUCK 391      // ceil(N/128) buckets of 128 consecutive dst nodes
#define BCAP  2816     // per-bucket staging capacity (mean 2046, sigma 45 -> +17 sigma)
#define CHUNK 2048     // edges per partition block (391 blocks)
#define BSLACK 384     // per-bucket perm4 padding slack (128 nodes * 3 max pad)

#define CVT_BLOCKS 12500   // 12500*256*2 == N_NODES*DIM exactly (2 elems/thread)

#define LDSROW 136     // Gs row stride in shorts (272 B: 2-way bank alias = free)

typedef float floatx4 __attribute__((ext_vector_type(4)));
typedef float floatx2 __attribute__((ext_vector_type(2)));
typedef short shortx8 __attribute__((ext_vector_type(8)));

__device__ __forceinline__ unsigned short f2bf(float f) {
    union { float f; unsigned int u; } c; c.f = f;
    unsigned int u = c.u;
    unsigned int r = (u + 0x7FFFu + ((u >> 16) & 1u)) >> 16;
    return (unsigned short)r;
}
__device__ __forceinline__ unsigned char f2fp8(float f) {
    unsigned int p = __builtin_amdgcn_cvt_pk_fp8_f32(f, f, 0u, false);
    return (unsigned char)(p & 0xFFu);
}

// ---------------------------------------------------------------------------
// prep: fused  x->bf16+fp8 convert | zero bcursor | weight pack
__global__ __launch_bounds__(256)
void prep_kernel(const float* __restrict__ x, unsigned short* __restrict__ X,
                 unsigned char* __restrict__ X8,
                 const float* __restrict__ wr0, const float* __restrict__ wt0,
                 const float* __restrict__ wr1, const float* __restrict__ wt1,
                 const float* __restrict__ wr2, const float* __restrict__ wt2,
                 unsigned short* __restrict__ Wp, int* __restrict__ bcursor) {
    int b = blockIdx.x;
    if (b < CVT_BLOCKS) {
        int i = (b * 256 + threadIdx.x) * 2;   // N*DIM exact multiple of 512
        float2 xv = *(const float2*)(x + i);
        *(unsigned int*)(X + i) =
            (unsigned int)f2bf(xv.x) | ((unsigned int)f2bf(xv.y) << 16);
        unsigned int p8 = __builtin_amdgcn_cvt_pk_fp8_f32(xv.x, xv.y, 0u, false);
        *(unsigned short*)(X8 + i) = (unsigned short)(p8 & 0xFFFFu);
    } else if (b == CVT_BLOCKS) {
        for (int i = threadIdx.x; i < NBUCK; i += 256) bcursor[i] = 0;
    } else {
        int id = (b - CVT_BLOCKS - 1) * 256 + threadIdx.x;   // < 3*32768
        int layer = id >> 15;
        int rem = id & 32767;
        int j  = rem & 7;
        int L  = (rem >> 3) & 63;
        int ct = (rem >> 9) & 7;
        int t  = rem >> 12;
        int k = t * 32 + (L >> 4) * 8 + j;
        int c = ct * 16 + (L & 15);
        const float* wr = (layer == 0) ? wr0 : (layer == 1) ? wr1 : wr2;
        const float* wt = (layer == 0) ? wt0 : (layer == 1) ? wt1 : wt2;
        float v = (k < 128) ? wr[k * 128 + c] : wt[(k - 128) * 128 + c];
        Wp[id] = f2bf(v);
    }
}

// Pass 1: bin edges by bucket (dst>>7) through LDS, contiguous runs to staging.
__global__ __launch_bounds__(1024)
void partition_kernel(const int* __restrict__ src, const int* __restrict__ dst,
                      const float* __restrict__ ew,
                      int* __restrict__ bcursor, int2* __restrict__ bstage, int e) {
    __shared__ int2 stage[CHUNK];      // 16 KB
    __shared__ int cnt[NBUCK];
    __shared__ int lbase[NBUCK];
    __shared__ int gbase[NBUCK];
    __shared__ int wsum[16];
    const int tid = threadIdx.x;
    const int e0 = blockIdx.x * CHUNK;
    const int ecnt = min(CHUNK, e - e0);

    for (int i = tid; i < NBUCK; i += 1024) cnt[i] = 0;
    __syncthreads();
    for (int i = tid; i < ecnt; i += 1024)
        atomicAdd(&cnt[dst[e0 + i] >> 7], 1);
    __syncthreads();

    {
        int v = (tid < NBUCK) ? cnt[tid] : 0;
        int lane = tid & 63, wid = tid >> 6;
        int acc = v;
#pragma unroll
        for (int off = 1; off < 64; off <<= 1) {
            int t = __shfl_up(acc, off, 64);
            if (lane >= off) acc += t;
        }
        if (lane == 63) wsum[wid] = acc;
        __syncthreads();
        int wpref = 0;
        for (int w = 0; w < wid; ++w) wpref += wsum[w];
        int excl = wpref + acc - v;
        if (tid < NBUCK) {
            lbase[tid] = excl;
            gbase[tid] = atomicAdd(&bcursor[tid], v);
            cnt[tid] = 0;            // reuse as local cursor
        }
    }
    __syncthreads();

    for (int i = tid; i < ecnt; i += 1024) {
        int d = dst[e0 + i];
        int s = src[e0 + i];
        unsigned int hw = (unsigned int)__half_as_ushort(__float2half(ew[e0 + i]));
        int b = d >> 7;
        int pos = atomicAdd(&cnt[b], 1);
        stage[lbase[b] + pos] = make_int2((int)((hw << 16) | (unsigned int)s), d);
    }
    __syncthreads();

    for (int j = tid; j < ecnt; j += 1024) {
        int2 p = stage[j];
        int b = p.y >> 7;
        int gidx = b * BCAP + gbase[b] + (j - lbase[b]);
        bstage[gidx] = p;
    }
}

// Pass 2: per bucket (128 nodes, 391 blocks), 512 threads.
// Per-node lists in perm4 are padded to a multiple of 4 (pad entries = 0:
// src 0, weight +0.0). Bucket b's perm4 window starts at rawScan(b) + b*BSLACK.
// row_start/row_end give each node's padded [beg,end).
__global__ __launch_bounds__(512)
void bucket_fill_kernel(const int2* __restrict__ bstage, const int* __restrict__ bcursor,
                        int* __restrict__ row_start, int* __restrict__ row_end,
                        unsigned int* __restrict__ perm4, int n) {
    __shared__ int cnt128[128];
    __shared__ int curs[128];
    __shared__ int wsum[8];
    __shared__ int sbase, scnt;
    const int tid = threadIdx.x;
    const int b = blockIdx.x;
    const int node0 = b << 7;
    const int lane = tid & 63, wid = tid >> 6;

    // exclusive prefix over 391 raw bucket totals, 1 entry per thread
    {
        int v = (tid < NBUCK) ? bcursor[tid] : 0;
        int acc = v;
#pragma unroll
        for (int off = 1; off < 64; off <<= 1) {
            int t = __shfl_up(acc, off, 64);
            if (lane >= off) acc += t;
        }
        if (lane == 63) wsum[wid] = acc;
        __syncthreads();
        int wpref = 0;
        for (int w = 0; w < wid; ++w) wpref += wsum[w];
        int excl = wpref + acc - v;
        if (tid == b) { sbase = excl; scnt = v; }
    }
    __syncthreads();
    const int cntb = scnt;
    const int base = sbase + b * BSLACK;     // padded slack per bucket
    const int2* sp = bstage + (size_t)b * BCAP;

    if (tid < 128) cnt128[tid] = 0;
    __syncthreads();
    for (int i = tid; i < cntb; i += 512)
        atomicAdd(&cnt128[sp[i].y & 127], 1);
    __syncthreads();

    // scan 128 per-node PADDED counts (first 2 waves carry data)
    int v = (tid < 128) ? cnt128[tid] : 0;
    int pcv = (v + 3) & ~3;
    int acc = pcv;
#pragma unroll
    for (int off = 1; off < 64; off <<= 1) {
        int t = __shfl_up(acc, off, 64);
        if (lane >= off) acc += t;
    }
    if (lane == 63) wsum[wid] = acc;
    __syncthreads();
    int wpref = 0;
    for (int w = 0; w < wid; ++w) wpref += wsum[w];
    int excl = wpref + acc - pcv;
    if (tid < 128) {
        int node = node0 + tid;
        if (node < n) {
            row_start[node] = base + excl;
            row_end[node]   = base + excl + pcv;
        }
        curs[tid] = excl;
        // zero-fill the <=3 pad slots so they read as (src 0, weight +0.0)
        for (int k = v; k < pcv; ++k) perm4[base + excl + k] = 0u;
    }
    __syncthreads();

    for (int i = tid; i < cntb; i += 512) {
        int2 p = sp[i];
        int pos = atomicAdd(&curs[p.y & 127], 1);
        perm4[base + pos] = (unsigned int)p.x;
    }
}

// ---------------------------------------------------------------------------
// Fused layer v11: BARRIER-FREE, sum-balanced waves.
//  - Wave = 8 nodes, fully autonomous (no __syncthreads anywhere).
//  - Each 16-lane group owns 2 consecutive nodes; their padded perm4 lists are
//    contiguous -> two guard-free pipelined segments (work ~ sum of degrees,
//    not max), flushed to the wave's private 8-row LDS strip.
//  - The wave alone runs its 8x128 GEMM on a 16x16x32 MFMA tile (A rows 8-15
//    duplicate rows 0-7; C rows 8-15 computed but not stored — MFMA util is
//    ~3%, the waste is cheaper than any barrier).
#define ACCQ(p, v) do { \
    float w_ = __half2float(__ushort_as_half((unsigned short)((p) >> 16))); \
    floatx2 W_ = (floatx2){w_, w_}; \
    floatx2 f0_ = __builtin_amdgcn_cvt_pk_f32_fp8((v).x, false); \
    floatx2 f1_ = __builtin_amdgcn_cvt_pk_f32_fp8((v).x, true);  \
    floatx2 f2_ = __builtin_amdgcn_cvt_pk_f32_fp8((v).y, false); \
    floatx2 f3_ = __builtin_amdgcn_cvt_pk_f32_fp8((v).y, true);  \
    ac[0] += W_ * f0_; ac[1] += W_ * f1_; \
    ac[2] += W_ * f2_; ac[3] += W_ * f3_; \
} while (0)

// accumulate padded segment [beg_,end_) of one node, flush to LDS row lr_
#define SEG(beg_, end_, lr_) do { \
    floatx2 ac[4]; \
    ac[0] = ac[1] = ac[2] = ac[3] = (floatx2){0.f, 0.f}; \
    const bool any = (beg_) < (end_); \
    uint4 P = {}; \
    uint2 v0 = {}, v1 = {}, v2 = {}, v3 = {}; \
    int t = (beg_); \
    if (any) { \
        P  = *(const uint4*)(perm4 + t); \
        v0 = *(const uint2*)(hp8 + (size_t)(P.x & 0xFFFFu) * DIM); \
        v1 = *(const uint2*)(hp8 + (size_t)(P.y & 0xFFFFu) * DIM); \
        v2 = *(const uint2*)(hp8 + (size_t)(P.z & 0xFFFFu) * DIM); \
        v3 = *(const uint2*)(hp8 + (size_t)(P.w & 0xFFFFu) * DIM); \
    } \
    for (; t + 4 < (end_); t += 4) { \
        uint4 Pn = *(const uint4*)(perm4 + t + 4); \
        uint2 w0 = *(const uint2*)(hp8 + (size_t)(Pn.x & 0xFFFFu) * DIM); \
        uint2 w1 = *(const uint2*)(hp8 + (size_t)(Pn.y & 0xFFFFu) * DIM); \
        uint2 w2 = *(const uint2*)(hp8 + (size_t)(Pn.z & 0xFFFFu) * DIM); \
        uint2 w3 = *(const uint2*)(hp8 + (size_t)(Pn.w & 0xFFFFu) * DIM); \
        ACCQ(P.x, v0); ACCQ(P.y, v1); ACCQ(P.z, v2); ACCQ(P.w, v3); \
        P = Pn; v0 = w0; v1 = w1; v2 = w2; v3 = w3; \
    } \
    if (any) { ACCQ(P.x, v0); ACCQ(P.y, v1); ACCQ(P.z, v2); ACCQ(P.w, v3); } \
    uint4 r; \
    r.x = (unsigned int)f2bf(ac[0].x) | ((unsigned int)f2bf(ac[0].y) << 16); \
    r.y = (unsigned int)f2bf(ac[1].x) | ((unsigned int)f2bf(ac[1].y) << 16); \
    r.z = (unsigned int)f2bf(ac[2].x) | ((unsigned int)f2bf(ac[2].y) << 16); \
    r.w = (unsigned int)f2bf(ac[3].x) | ((unsigned int)f2bf(ac[3].y) << 16); \
    *(uint4*)(&Gs[(size_t)(lr_) * LDSROW + sl * 8]) = r; \
} while (0)

__global__ __launch_bounds__(256, 5)
void fused_layer(const unsigned short* __restrict__ h, const unsigned char* __restrict__ h8,
                 const int* __restrict__ row_start, const int* __restrict__ row_end,
                 const unsigned int* __restrict__ perm4, const unsigned short* __restrict__ Wp,
                 const float* __restrict__ bias, float* __restrict__ outF,
                 unsigned short* __restrict__ outB, unsigned char* __restrict__ outB8,
                 int relu) {
    __shared__ unsigned short Gs[32 * LDSROW];   // 4 waves x 8 rows, 8.5 KB
    const int tid  = threadIdx.x;
    const int lane = tid & 63;
    const int wid  = tid >> 6;
    const int g  = lane >> 4;      // group (2 nodes in phase1) / k-quad (phase2)
    const int sl = lane & 15;      // col-chunk (phase1) / A-row (phase2)
    const int waveBase = blockIdx.x * 32 + wid * 8;
    if (waveBase >= N_NODES) return;          // tail waves: safe, no barriers
    const int n0 = waveBase + g * 2;          // group's nodes n0, n0+1

    // group boundaries: lists of n0 and n0+1 are contiguous (padded CSR)
    int rs = 0;
    if (sl < 2)       rs = row_start[n0 + sl];
    else if (sl == 2) rs = row_end[n0 + 1];
    const int gb = g << 4;
    const int s0 = __shfl(rs, gb + 0, 64);
    const int s1 = __shfl(rs, gb + 1, 64);   // end of n0 == start of n0+1
    const int s2 = __shfl(rs, gb + 2, 64);

    // ---- phase 1: two pipelined segments, flush to wave's LDS strip ----
    const unsigned char* hp8 = h8 + sl * 8;
    unsigned short* GsW = Gs;   // alias; rows indexed wave-locally below
    {
        const int lr0 = wid * 8 + g * 2;
        SEG(s0, s1, lr0);
        SEG(s1, s2, lr0 + 1);
    }
    (void)GsW;

    // ---- phase 2: wave-private GEMM, no barrier (own LDS strip only) ----
    floatx4 acc2[8];
#pragma unroll
    for (int ct = 0; ct < 8; ++ct) acc2[ct] = (floatx4){0.f, 0.f, 0.f, 0.f};
    const int arow = wid * 8 + (sl & 7);       // A rows 8-15 duplicate 0-7
    const int rr = waveBase + (sl & 7);
    const int ko = g * 8;
#pragma unroll
    for (int t2 = 0; t2 < 8; ++t2) {
        shortx8 a;
        if (t2 < 4)
            a = *(const shortx8*)(&Gs[(size_t)arow * LDSROW + t2 * 32 + ko]);
        else
            a = *(const shortx8*)(h + (size_t)rr * DIM + (t2 - 4) * 32 + ko);
        const unsigned short* wp = Wp + (size_t)t2 * 4096 + lane * 8;
#pragma unroll
        for (int ct = 0; ct < 8; ++ct) {
            shortx8 b = *(const shortx8*)(wp + ct * 512);
            acc2[ct] = __builtin_amdgcn_mfma_f32_16x16x32_bf16(a, b, acc2[ct], 0, 0, 0);
        }
    }

    // ---- store: C rows 0-7 only (rows 8-15 are the duplicate-garbage) ----
    if (g < 2) {
#pragma unroll
        for (int ct = 0; ct < 8; ++ct) {
            int col = ct * 16 + sl;
            float bv = bias[col];
#pragma unroll
            for (int i = 0; i < 4; ++i) {
                int row = waveBase + g * 4 + i;
                float v = acc2[ct][i] + bv;
                if (relu) v = fmaxf(v, 0.f);
                if (outF) {
                    outF[(size_t)row * DIM + col] = v;
                } else {
                    outB[(size_t)row * DIM + col]  = f2bf(v);
                    outB8[(size_t)row * DIM + col] = f2fp8(v);
                }
            }
        }
    }
}

extern "C" void kernel_launch(void* const* d_in, const int* in_sizes, int n_in,
                              void* d_out, int out_size, void* d_ws, size_t ws_size,
                              hipStream_t stream) {
    const int N = N_NODES, E = N_EDGES;

    const float* x   = (const float*)d_in[0];
    const int*   ei  = (const int*)d_in[1];
    const float* ea  = (const float*)d_in[2];
    const float* wr0 = (const float*)d_in[3];
    const float* br0 = (const float*)d_in[4];
    const float* wt0 = (const float*)d_in[5];
    const float* wr1 = (const float*)d_in[6];
    const float* br1 = (const float*)d_in[7];
    const float* wt1 = (const float*)d_in[8];
    const float* wr2 = (const float*)d_in[9];
    const float* br2 = (const float*)d_in[10];
    const float* wt2 = (const float*)d_in[11];
    const int* srcI = ei;
    const int* dstI = ei + E;
    float* out = (float*)d_out;

    // workspace layout — every array before the fp8 tables has a size that is
    // a multiple of 128 B, so X8/H81/H82 rows are 128B-aligned (1 line/row),
    // and perm4 is 128B-aligned (dwordx4 quad loads).
    int2* bstage = (int2*)d_ws;                              // 391*2816*8 = 8,808,448 B
    unsigned short* X  = (unsigned short*)(bstage + (size_t)NBUCK * BCAP);  // 12.8 MB
    unsigned short* H1 = X + (size_t)N * DIM;                // 12.8 MB
    unsigned short* H2 = H1 + (size_t)N * DIM;               // 12.8 MB
    unsigned short* Wp = H2 + (size_t)N * DIM;               // 196,608 B
    unsigned char* X8  = (unsigned char*)(Wp + 3 * 32768);   // 6.4 MB (128B-aligned)
    unsigned char* H81 = X8 + (size_t)N * DIM;               // 6.4 MB
    unsigned char* H82 = H81 + (size_t)N * DIM;              // 6.4 MB
    unsigned int* perm4 = (unsigned int*)(H82 + (size_t)N * DIM);  // E + NBUCK*BSLACK (<1M) u32
    int* bcursor = (int*)(perm4 + 1000000);                  // NBUCK i32
    int* rowst   = bcursor + NBUCK;                          // N i32
    int* rowend  = rowst + N_NODES;                          // N i32

    // prep (cvt + zero + pack) and CSR build via binned counting sort
    prep_kernel<<<CVT_BLOCKS + 1 + 384, 256, 0, stream>>>(x, X, X8, wr0, wt0, wr1, wt1, wr2, wt2, Wp, bcursor);
    partition_kernel<<<(E + CHUNK - 1) / CHUNK, 1024, 0, stream>>>(srcI, dstI, ea, bcursor, bstage, E);
    bucket_fill_kernel<<<NBUCK, 512, 0, stream>>>(bstage, bcursor, rowst, rowend, perm4, N);

    const int fusedGrid = (N + 31) / 32;     // 1563 blocks, 32 nodes (4 waves)

    // ping-pong h buffers: gathers read prev layer's fp8 copy
    fused_layer<<<fusedGrid, 256, 0, stream>>>(X,  X8,  rowst, rowend, perm4, Wp,         br0, nullptr, H1, H81, 1);
    fused_layer<<<fusedGrid, 256, 0, stream>>>(H1, H81, rowst, rowend, perm4, Wp + 32768, br1, nullptr, H2, H82, 1);
    fused_layer<<<fusedGrid, 256, 0, stream>>>(H2, H82, rowst, rowend, perm4, Wp + 65536, br2, out, nullptr, nullptr, 0);
}

// Round 10
// 212.833 us; speedup vs baseline: 1.2230x; 1.0935x over previous
//
#include <hip/hip_runtime.h>
#include <hip/hip_bf16.h>
#include <hip/hip_fp16.h>

#define N_NODES 50000
#define N_EDGES 800000
#define DIM 128

#define NBUCK 391      // ceil(N/128) buckets of 128 consecutive dst nodes
#define BCAP  2816     // per-bucket staging capacity (mean 2046, sigma 45 -> +17 sigma)
#define CHUNK 2048     // edges per partition block (391 blocks)
#define BSLACK 384     // per-bucket perm4 padding slack (128 nodes * 3 max pad)

#define CVT_BLOCKS 12500   // 12500*256*2 == N_NODES*DIM exactly (2 elems/thread)

#define LDSROW 136     // Gs row stride in shorts (272 B: 2-way bank alias = free)

typedef float floatx4 __attribute__((ext_vector_type(4)));
typedef float floatx2 __attribute__((ext_vector_type(2)));
typedef short shortx8 __attribute__((ext_vector_type(8)));

__device__ __forceinline__ unsigned short f2bf(float f) {
    union { float f; unsigned int u; } c; c.f = f;
    unsigned int u = c.u;
    unsigned int r = (u + 0x7FFFu + ((u >> 16) & 1u)) >> 16;
    return (unsigned short)r;
}
__device__ __forceinline__ unsigned char f2fp8(float f) {
    unsigned int p = __builtin_amdgcn_cvt_pk_fp8_f32(f, f, 0u, false);
    return (unsigned char)(p & 0xFFu);
}

// ---------------------------------------------------------------------------
// prep: fused  x->bf16+fp8 convert | zero bcursor | weight pack
__global__ __launch_bounds__(256)
void prep_kernel(const float* __restrict__ x, unsigned short* __restrict__ X,
                 unsigned char* __restrict__ X8,
                 const float* __restrict__ wr0, const float* __restrict__ wt0,
                 const float* __restrict__ wr1, const float* __restrict__ wt1,
                 const float* __restrict__ wr2, const float* __restrict__ wt2,
                 unsigned short* __restrict__ Wp, int* __restrict__ bcursor) {
    int b = blockIdx.x;
    if (b < CVT_BLOCKS) {
        int i = (b * 256 + threadIdx.x) * 2;   // N*DIM exact multiple of 512
        float2 xv = *(const float2*)(x + i);
        *(unsigned int*)(X + i) =
            (unsigned int)f2bf(xv.x) | ((unsigned int)f2bf(xv.y) << 16);
        unsigned int p8 = __builtin_amdgcn_cvt_pk_fp8_f32(xv.x, xv.y, 0u, false);
        *(unsigned short*)(X8 + i) = (unsigned short)(p8 & 0xFFFFu);
    } else if (b == CVT_BLOCKS) {
        for (int i = threadIdx.x; i < NBUCK; i += 256) bcursor[i] = 0;
    } else {
        int id = (b - CVT_BLOCKS - 1) * 256 + threadIdx.x;   // < 3*32768
        int layer = id >> 15;
        int rem = id & 32767;
        int j  = rem & 7;
        int L  = (rem >> 3) & 63;
        int ct = (rem >> 9) & 7;
        int t  = rem >> 12;
        int k = t * 32 + (L >> 4) * 8 + j;
        int c = ct * 16 + (L & 15);
        const float* wr = (layer == 0) ? wr0 : (layer == 1) ? wr1 : wr2;
        const float* wt = (layer == 0) ? wt0 : (layer == 1) ? wt1 : wt2;
        float v = (k < 128) ? wr[k * 128 + c] : wt[(k - 128) * 128 + c];
        Wp[id] = f2bf(v);
    }
}

// Pass 1: bin edges by bucket (dst>>7) through LDS, contiguous runs to staging.
__global__ __launch_bounds__(1024)
void partition_kernel(const int* __restrict__ src, const int* __restrict__ dst,
                      const float* __restrict__ ew,
                      int* __restrict__ bcursor, int2* __restrict__ bstage, int e) {
    __shared__ int2 stage[CHUNK];      // 16 KB
    __shared__ int cnt[NBUCK];
    __shared__ int lbase[NBUCK];
    __shared__ int gbase[NBUCK];
    __shared__ int wsum[16];
    const int tid = threadIdx.x;
    const int e0 = blockIdx.x * CHUNK;
    const int ecnt = min(CHUNK, e - e0);

    for (int i = tid; i < NBUCK; i += 1024) cnt[i] = 0;
    __syncthreads();
    for (int i = tid; i < ecnt; i += 1024)
        atomicAdd(&cnt[dst[e0 + i] >> 7], 1);
    __syncthreads();

    {
        int v = (tid < NBUCK) ? cnt[tid] : 0;
        int lane = tid & 63, wid = tid >> 6;
        int acc = v;
#pragma unroll
        for (int off = 1; off < 64; off <<= 1) {
            int t = __shfl_up(acc, off, 64);
            if (lane >= off) acc += t;
        }
        if (lane == 63) wsum[wid] = acc;
        __syncthreads();
        int wpref = 0;
        for (int w = 0; w < wid; ++w) wpref += wsum[w];
        int excl = wpref + acc - v;
        if (tid < NBUCK) {
            lbase[tid] = excl;
            gbase[tid] = atomicAdd(&bcursor[tid], v);
            cnt[tid] = 0;            // reuse as local cursor
        }
    }
    __syncthreads();

    for (int i = tid; i < ecnt; i += 1024) {
        int d = dst[e0 + i];
        int s = src[e0 + i];
        unsigned int hw = (unsigned int)__half_as_ushort(__float2half(ew[e0 + i]));
        int b = d >> 7;
        int pos = atomicAdd(&cnt[b], 1);
        stage[lbase[b] + pos] = make_int2((int)((hw << 16) | (unsigned int)s), d);
    }
    __syncthreads();

    for (int j = tid; j < ecnt; j += 1024) {
        int2 p = stage[j];
        int b = p.y >> 7;
        int gidx = b * BCAP + gbase[b] + (j - lbase[b]);
        bstage[gidx] = p;
    }
}

// Pass 2: per bucket (128 nodes, 391 blocks), 512 threads.
// Per-node lists in perm4 are padded to a multiple of 4 (pad entries = 0:
// src 0, weight +0.0). Bucket b's perm4 window starts at rawScan(b) + b*BSLACK.
// row_start/row_end give each node's padded [beg,end).
__global__ __launch_bounds__(512)
void bucket_fill_kernel(const int2* __restrict__ bstage, const int* __restrict__ bcursor,
                        int* __restrict__ row_start, int* __restrict__ row_end,
                        unsigned int* __restrict__ perm4, int n) {
    __shared__ int cnt128[128];
    __shared__ int curs[128];
    __shared__ int wsum[8];
    __shared__ int sbase, scnt;
    const int tid = threadIdx.x;
    const int b = blockIdx.x;
    const int node0 = b << 7;
    const int lane = tid & 63, wid = tid >> 6;

    // exclusive prefix over 391 raw bucket totals, 1 entry per thread
    {
        int v = (tid < NBUCK) ? bcursor[tid] : 0;
        int acc = v;
#pragma unroll
        for (int off = 1; off < 64; off <<= 1) {
            int t = __shfl_up(acc, off, 64);
            if (lane >= off) acc += t;
        }
        if (lane == 63) wsum[wid] = acc;
        __syncthreads();
        int wpref = 0;
        for (int w = 0; w < wid; ++w) wpref += wsum[w];
        int excl = wpref + acc - v;
        if (tid == b) { sbase = excl; scnt = v; }
    }
    __syncthreads();
    const int cntb = scnt;
    const int base = sbase + b * BSLACK;     // padded slack per bucket
    const int2* sp = bstage + (size_t)b * BCAP;

    if (tid < 128) cnt128[tid] = 0;
    __syncthreads();
    for (int i = tid; i < cntb; i += 512)
        atomicAdd(&cnt128[sp[i].y & 127], 1);
    __syncthreads();

    // scan 128 per-node PADDED counts (first 2 waves carry data)
    int v = (tid < 128) ? cnt128[tid] : 0;
    int pcv = (v + 3) & ~3;
    int acc = pcv;
#pragma unroll
    for (int off = 1; off < 64; off <<= 1) {
        int t = __shfl_up(acc, off, 64);
        if (lane >= off) acc += t;
    }
    if (lane == 63) wsum[wid] = acc;
    __syncthreads();
    int wpref = 0;
    for (int w = 0; w < wid; ++w) wpref += wsum[w];
    int excl = wpref + acc - pcv;
    if (tid < 128) {
        int node = node0 + tid;
        if (node < n) {
            row_start[node] = base + excl;
            row_end[node]   = base + excl + pcv;
        }
        curs[tid] = excl;
        // zero-fill the <=3 pad slots so they read as (src 0, weight +0.0)
        for (int k = v; k < pcv; ++k) perm4[base + excl + k] = 0u;
    }
    __syncthreads();

    for (int i = tid; i < cntb; i += 512) {
        int2 p = sp[i];
        int pos = atomicAdd(&curs[p.y & 127], 1);
        perm4[base + pos] = (unsigned int)p.x;
    }
}

// ---------------------------------------------------------------------------
// Fused layer v12: block = 32 nodes (4 waves), ONE barrier.
// Phase 1: each 16-lane group owns 2 CONTIGUOUS nodes -> two guard-free
//          pipelined segments (wave time ~ max of sums-of-2, lower variance
//          than max of singles). Flush to block-global LDS rows.
// Phase 1.5: root-GEMM (2 A-tiles, B fragments reused) before the barrier.
// Phase 2: aggregate-GEMM from LDS; each wave does cols [32w,32w+32) over
//          32 rows. MFMA per node unchanged vs v9; weight traffic halved.
#define ACCQ(p, v) do { \
    float w_ = __half2float(__ushort_as_half((unsigned short)((p) >> 16))); \
    floatx2 W_ = (floatx2){w_, w_}; \
    floatx2 f0_ = __builtin_amdgcn_cvt_pk_f32_fp8((v).x, false); \
    floatx2 f1_ = __builtin_amdgcn_cvt_pk_f32_fp8((v).x, true);  \
    floatx2 f2_ = __builtin_amdgcn_cvt_pk_f32_fp8((v).y, false); \
    floatx2 f3_ = __builtin_amdgcn_cvt_pk_f32_fp8((v).y, true);  \
    ac[0] += W_ * f0_; ac[1] += W_ * f1_; \
    ac[2] += W_ * f2_; ac[3] += W_ * f3_; \
} while (0)

// accumulate padded segment [beg_,end_) of one node, flush to LDS row lr_
#define SEG(beg_, end_, lr_) do { \
    floatx2 ac[4]; \
    ac[0] = ac[1] = ac[2] = ac[3] = (floatx2){0.f, 0.f}; \
    const bool any = (beg_) < (end_); \
    uint4 P = {}; \
    uint2 v0 = {}, v1 = {}, v2 = {}, v3 = {}; \
    int t = (beg_); \
    if (any) { \
        P  = *(const uint4*)(perm4 + t); \
        v0 = *(const uint2*)(hp8 + (size_t)(P.x & 0xFFFFu) * DIM); \
        v1 = *(const uint2*)(hp8 + (size_t)(P.y & 0xFFFFu) * DIM); \
        v2 = *(const uint2*)(hp8 + (size_t)(P.z & 0xFFFFu) * DIM); \
        v3 = *(const uint2*)(hp8 + (size_t)(P.w & 0xFFFFu) * DIM); \
    } \
    for (; t + 4 < (end_); t += 4) { \
        uint4 Pn = *(const uint4*)(perm4 + t + 4); \
        uint2 w0 = *(const uint2*)(hp8 + (size_t)(Pn.x & 0xFFFFu) * DIM); \
        uint2 w1 = *(const uint2*)(hp8 + (size_t)(Pn.y & 0xFFFFu) * DIM); \
        uint2 w2 = *(const uint2*)(hp8 + (size_t)(Pn.z & 0xFFFFu) * DIM); \
        uint2 w3 = *(const uint2*)(hp8 + (size_t)(Pn.w & 0xFFFFu) * DIM); \
        ACCQ(P.x, v0); ACCQ(P.y, v1); ACCQ(P.z, v2); ACCQ(P.w, v3); \
        P = Pn; v0 = w0; v1 = w1; v2 = w2; v3 = w3; \
    } \
    if (any) { ACCQ(P.x, v0); ACCQ(P.y, v1); ACCQ(P.z, v2); ACCQ(P.w, v3); } \
    uint4 r; \
    r.x = (unsigned int)f2bf(ac[0].x) | ((unsigned int)f2bf(ac[0].y) << 16); \
    r.y = (unsigned int)f2bf(ac[1].x) | ((unsigned int)f2bf(ac[1].y) << 16); \
    r.z = (unsigned int)f2bf(ac[2].x) | ((unsigned int)f2bf(ac[2].y) << 16); \
    r.w = (unsigned int)f2bf(ac[3].x) | ((unsigned int)f2bf(ac[3].y) << 16); \
    *(uint4*)(&Gs[(size_t)(lr_) * LDSROW + sl * 8]) = r; \
} while (0)

__global__ __launch_bounds__(256, 6)
void fused_layer(const unsigned short* __restrict__ h, const unsigned char* __restrict__ h8,
                 const int* __restrict__ row_start, const int* __restrict__ row_end,
                 const unsigned int* __restrict__ perm4, const unsigned short* __restrict__ Wp,
                 const float* __restrict__ bias, float* __restrict__ outF,
                 unsigned short* __restrict__ outB, unsigned char* __restrict__ outB8,
                 int relu) {
    __shared__ unsigned short Gs[32 * LDSROW];   // 8.5 KB
    const int tid  = threadIdx.x;
    const int lane = tid & 63;
    const int wid  = tid >> 6;
    const int g  = lane >> 4;      // group (2 nodes in phase1) / k-quad (phase2)
    const int sl = lane & 15;      // col-chunk (phase1) / A-row (phase2)
    const int rowT = blockIdx.x * 32;
    const int waveBase = rowT + wid * 8;
    const int n0 = waveBase + g * 2;          // group's nodes n0, n0+1

    // group boundaries: lists of n0 and n0+1 are contiguous (padded CSR;
    // a 32-node block never crosses a 128-node bucket boundary).
    int rs = 0;
    if (sl < 2)       rs = row_start[min(n0 + sl, N_NODES - 1)];
    else if (sl == 2) rs = row_end[min(n0 + 1, N_NODES - 1)];
    const int gb = g << 4;
    int s0 = __shfl(rs, gb + 0, 64);
    int s1 = __shfl(rs, gb + 1, 64);   // end of n0 == start of n0+1
    int s2 = __shfl(rs, gb + 2, 64);
    if (n0 >= N_NODES) { s0 = 0; s1 = 0; s2 = 0; }   // tail: zero segments

    // ---- phase 1: two pipelined segments, flush to block LDS rows ----
    const unsigned char* hp8 = h8 + sl * 8;
    {
        const int lr0 = wid * 8 + g * 2;
        SEG(s0, s1, lr0);
        SEG(s1, s2, lr0 + 1);
    }

    // ---- phase 1.5: root-GEMM (2 A-tiles, shared B), no LDS dependency ----
    floatx4 acc2[4];    // [tile*2 + ct]
#pragma unroll
    for (int q = 0; q < 4; ++q) acc2[q] = (floatx4){0.f, 0.f, 0.f, 0.f};
    const int rr0 = min(rowT + sl,      N_NODES - 1);
    const int rr1 = min(rowT + 16 + sl, N_NODES - 1);
    const int ko = g * 8;
#pragma unroll
    for (int t2 = 4; t2 < 8; ++t2) {
        shortx8 a0 = *(const shortx8*)(h + (size_t)rr0 * DIM + (t2 - 4) * 32 + ko);
        shortx8 a1 = *(const shortx8*)(h + (size_t)rr1 * DIM + (t2 - 4) * 32 + ko);
        const unsigned short* wp = Wp + (size_t)t2 * 4096 + (wid * 2) * 512 + lane * 8;
#pragma unroll
        for (int ct = 0; ct < 2; ++ct) {
            shortx8 b = *(const shortx8*)(wp + ct * 512);
            acc2[ct]     = __builtin_amdgcn_mfma_f32_16x16x32_bf16(a0, b, acc2[ct], 0, 0, 0);
            acc2[2 + ct] = __builtin_amdgcn_mfma_f32_16x16x32_bf16(a1, b, acc2[2 + ct], 0, 0, 0);
        }
    }

    __syncthreads();   // waves now read LDS rows written by other waves

    // ---- phase 2: aggregate-GEMM from LDS (2 A-tiles, shared B) ----
#pragma unroll
    for (int t2 = 0; t2 < 4; ++t2) {
        shortx8 a0 = *(const shortx8*)(&Gs[(size_t)sl * LDSROW + t2 * 32 + ko]);
        shortx8 a1 = *(const shortx8*)(&Gs[(size_t)(16 + sl) * LDSROW + t2 * 32 + ko]);
        const unsigned short* wp = Wp + (size_t)t2 * 4096 + (wid * 2) * 512 + lane * 8;
#pragma unroll
        for (int ct = 0; ct < 2; ++ct) {
            shortx8 b = *(const shortx8*)(wp + ct * 512);
            acc2[ct]     = __builtin_amdgcn_mfma_f32_16x16x32_bf16(a0, b, acc2[ct], 0, 0, 0);
            acc2[2 + ct] = __builtin_amdgcn_mfma_f32_16x16x32_bf16(a1, b, acc2[2 + ct], 0, 0, 0);
        }
    }

#pragma unroll
    for (int tile = 0; tile < 2; ++tile) {
#pragma unroll
        for (int ct = 0; ct < 2; ++ct) {
            int col = wid * 32 + ct * 16 + sl;
            float bv = bias[col];
#pragma unroll
            for (int i = 0; i < 4; ++i) {
                int row = rowT + tile * 16 + g * 4 + i;
                if (row < N_NODES) {
                    float v = acc2[tile * 2 + ct][i] + bv;
                    if (relu) v = fmaxf(v, 0.f);
                    if (outF) {
                        outF[(size_t)row * DIM + col] = v;
                    } else {
                        outB[(size_t)row * DIM + col]  = f2bf(v);
                        outB8[(size_t)row * DIM + col] = f2fp8(v);
                    }
                }
            }
        }
    }
}

extern "C" void kernel_launch(void* const* d_in, const int* in_sizes, int n_in,
                              void* d_out, int out_size, void* d_ws, size_t ws_size,
                              hipStream_t stream) {
    const int N = N_NODES, E = N_EDGES;

    const float* x   = (const float*)d_in[0];
    const int*   ei  = (const int*)d_in[1];
    const float* ea  = (const float*)d_in[2];
    const float* wr0 = (const float*)d_in[3];
    const float* br0 = (const float*)d_in[4];
    const float* wt0 = (const float*)d_in[5];
    const float* wr1 = (const float*)d_in[6];
    const float* br1 = (const float*)d_in[7];
    const float* wt1 = (const float*)d_in[8];
    const float* wr2 = (const float*)d_in[9];
    const float* br2 = (const float*)d_in[10];
    const float* wt2 = (const float*)d_in[11];
    const int* srcI = ei;
    const int* dstI = ei + E;
    float* out = (float*)d_out;

    // workspace layout — every array before the fp8 tables has a size that is
    // a multiple of 128 B, so X8/H81/H82 rows are 128B-aligned,
    // and perm4 is 128B-aligned (dwordx4 quad loads).
    int2* bstage = (int2*)d_ws;                              // 391*2816*8 = 8,808,448 B
    unsigned short* X  = (unsigned short*)(bstage + (size_t)NBUCK * BCAP);  // 12.8 MB
    unsigned short* H1 = X + (size_t)N * DIM;                // 12.8 MB
    unsigned short* H2 = H1 + (size_t)N * DIM;               // 12.8 MB
    unsigned short* Wp = H2 + (size_t)N * DIM;               // 196,608 B
    unsigned char* X8  = (unsigned char*)(Wp + 3 * 32768);   // 6.4 MB (128B-aligned)
    unsigned char* H81 = X8 + (size_t)N * DIM;               // 6.4 MB
    unsigned char* H82 = H81 + (size_t)N * DIM;              // 6.4 MB
    unsigned int* perm4 = (unsigned int*)(H82 + (size_t)N * DIM);  // E + NBUCK*BSLACK (<1M) u32
    int* bcursor = (int*)(perm4 + 1000000);                  // NBUCK i32
    int* rowst   = bcursor + NBUCK;                          // N i32
    int* rowend  = rowst + N_NODES;                          // N i32

    // prep (cvt + zero + pack) and CSR build via binned counting sort
    prep_kernel<<<CVT_BLOCKS + 1 + 384, 256, 0, stream>>>(x, X, X8, wr0, wt0, wr1, wt1, wr2, wt2, Wp, bcursor);
    partition_kernel<<<(E + CHUNK - 1) / CHUNK, 1024, 0, stream>>>(srcI, dstI, ea, bcursor, bstage, E);
    bucket_fill_kernel<<<NBUCK, 512, 0, stream>>>(bstage, bcursor, rowst, rowend, perm4, N);

    const int fusedGrid = (N + 31) / 32;     // 1563 blocks, 32 rows each

    // ping-pong h buffers: gathers read prev layer's fp8 copy
    fused_layer<<<fusedGrid, 256, 0, stream>>>(X,  X8,  rowst, rowend, perm4, Wp,         br0, nullptr, H1, H81, 1);
    fused_layer<<<fusedGrid, 256, 0, stream>>>(H1, H81, rowst, rowend, perm4, Wp + 32768, br1, nullptr, H2, H82, 1);
    fused_layer<<<fusedGrid, 256, 0, stream>>>(H2, H82, rowst, rowend, perm4, Wp + 65536, br2, out, nullptr, nullptr, 0);
}

// Round 11
// 210.659 us; speedup vs baseline: 1.2356x; 1.0103x over previous
//
#include <hip/hip_runtime.h>
#include <hip/hip_bf16.h>
#include <hip/hip_fp16.h>

#define N_NODES 50000
#define N_EDGES 800000
#define DIM 128

#define NBUCK 391      // ceil(N/128) buckets of 128 consecutive dst nodes
#define BCAP  2816     // per-bucket staging capacity (mean 2046, sigma 45 -> +17 sigma)
#define CHUNK 2048     // edges per partition block (391 blocks)
#define BSLACK 384     // per-bucket perm4 padding slack (128 nodes * 3 max pad)

#define CVT_BLOCKS 12500   // 12500*256*2 == N_NODES*DIM exactly (2 elems/thread)

#define LDSROW 136     // Gs row stride in shorts (272 B: 2-way bank alias = free)

typedef float floatx4 __attribute__((ext_vector_type(4)));
typedef float floatx2 __attribute__((ext_vector_type(2)));
typedef short shortx8 __attribute__((ext_vector_type(8)));

__device__ __forceinline__ unsigned short f2bf(float f) {
    union { float f; unsigned int u; } c; c.f = f;
    unsigned int u = c.u;
    unsigned int r = (u + 0x7FFFu + ((u >> 16) & 1u)) >> 16;
    return (unsigned short)r;
}
__device__ __forceinline__ unsigned char f2fp8(float f) {
    unsigned int p = __builtin_amdgcn_cvt_pk_fp8_f32(f, f, 0u, false);
    return (unsigned char)(p & 0xFFu);
}

// ---------------------------------------------------------------------------
// prep: fused  x->bf16+fp8 convert | zero bcursor | weight pack
__global__ __launch_bounds__(256)
void prep_kernel(const float* __restrict__ x, unsigned short* __restrict__ X,
                 unsigned char* __restrict__ X8,
                 const float* __restrict__ wr0, const float* __restrict__ wt0,
                 const float* __restrict__ wr1, const float* __restrict__ wt1,
                 const float* __restrict__ wr2, const float* __restrict__ wt2,
                 unsigned short* __restrict__ Wp, int* __restrict__ bcursor) {
    int b = blockIdx.x;
    if (b < CVT_BLOCKS) {
        int i = (b * 256 + threadIdx.x) * 2;   // N*DIM exact multiple of 512
        float2 xv = *(const float2*)(x + i);
        *(unsigned int*)(X + i) =
            (unsigned int)f2bf(xv.x) | ((unsigned int)f2bf(xv.y) << 16);
        unsigned int p8 = __builtin_amdgcn_cvt_pk_fp8_f32(xv.x, xv.y, 0u, false);
        *(unsigned short*)(X8 + i) = (unsigned short)(p8 & 0xFFFFu);
    } else if (b == CVT_BLOCKS) {
        for (int i = threadIdx.x; i < NBUCK; i += 256) bcursor[i] = 0;
    } else {
        int id = (b - CVT_BLOCKS - 1) * 256 + threadIdx.x;   // < 3*32768
        int layer = id >> 15;
        int rem = id & 32767;
        int j  = rem & 7;
        int L  = (rem >> 3) & 63;
        int ct = (rem >> 9) & 7;
        int t  = rem >> 12;
        int k = t * 32 + (L >> 4) * 8 + j;
        int c = ct * 16 + (L & 15);
        const float* wr = (layer == 0) ? wr0 : (layer == 1) ? wr1 : wr2;
        const float* wt = (layer == 0) ? wt0 : (layer == 1) ? wt1 : wt2;
        float v = (k < 128) ? wr[k * 128 + c] : wt[(k - 128) * 128 + c];
        Wp[id] = f2bf(v);
    }
}

// Pass 1: bin edges by bucket (dst>>7) through LDS, contiguous runs to staging.
__global__ __launch_bounds__(1024)
void partition_kernel(const int* __restrict__ src, const int* __restrict__ dst,
                      const float* __restrict__ ew,
                      int* __restrict__ bcursor, int2* __restrict__ bstage, int e) {
    __shared__ int2 stage[CHUNK];      // 16 KB
    __shared__ int cnt[NBUCK];
    __shared__ int lbase[NBUCK];
    __shared__ int gbase[NBUCK];
    __shared__ int wsum[16];
    const int tid = threadIdx.x;
    const int e0 = blockIdx.x * CHUNK;
    const int ecnt = min(CHUNK, e - e0);

    for (int i = tid; i < NBUCK; i += 1024) cnt[i] = 0;
    __syncthreads();
    for (int i = tid; i < ecnt; i += 1024)
        atomicAdd(&cnt[dst[e0 + i] >> 7], 1);
    __syncthreads();

    {
        int v = (tid < NBUCK) ? cnt[tid] : 0;
        int lane = tid & 63, wid = tid >> 6;
        int acc = v;
#pragma unroll
        for (int off = 1; off < 64; off <<= 1) {
            int t = __shfl_up(acc, off, 64);
            if (lane >= off) acc += t;
        }
        if (lane == 63) wsum[wid] = acc;
        __syncthreads();
        int wpref = 0;
        for (int w = 0; w < wid; ++w) wpref += wsum[w];
        int excl = wpref + acc - v;
        if (tid < NBUCK) {
            lbase[tid] = excl;
            gbase[tid] = atomicAdd(&bcursor[tid], v);
            cnt[tid] = 0;            // reuse as local cursor
        }
    }
    __syncthreads();

    for (int i = tid; i < ecnt; i += 1024) {
        int d = dst[e0 + i];
        int s = src[e0 + i];
        unsigned int hw = (unsigned int)__half_as_ushort(__float2half(ew[e0 + i]));
        int b = d >> 7;
        int pos = atomicAdd(&cnt[b], 1);
        stage[lbase[b] + pos] = make_int2((int)((hw << 16) | (unsigned int)s), d);
    }
    __syncthreads();

    for (int j = tid; j < ecnt; j += 1024) {
        int2 p = stage[j];
        int b = p.y >> 7;
        int gidx = b * BCAP + gbase[b] + (j - lbase[b]);
        bstage[gidx] = p;
    }
}

// Pass 2: per bucket (128 nodes, 391 blocks), 512 threads.
// Per-node lists in perm4 are padded to a multiple of 4 (pad entries = 0:
// src 0, weight +0.0). Bucket b's perm4 window starts at rawScan(b) + b*BSLACK.
// row_start/row_end give each node's padded [beg,end).
__global__ __launch_bounds__(512)
void bucket_fill_kernel(const int2* __restrict__ bstage, const int* __restrict__ bcursor,
                        int* __restrict__ row_start, int* __restrict__ row_end,
                        unsigned int* __restrict__ perm4, int n) {
    __shared__ int cnt128[128];
    __shared__ int curs[128];
    __shared__ int wsum[8];
    __shared__ int sbase, scnt;
    const int tid = threadIdx.x;
    const int b = blockIdx.x;
    const int node0 = b << 7;
    const int lane = tid & 63, wid = tid >> 6;

    // exclusive prefix over 391 raw bucket totals, 1 entry per thread
    {
        int v = (tid < NBUCK) ? bcursor[tid] : 0;
        int acc = v;
#pragma unroll
        for (int off = 1; off < 64; off <<= 1) {
            int t = __shfl_up(acc, off, 64);
            if (lane >= off) acc += t;
        }
        if (lane == 63) wsum[wid] = acc;
        __syncthreads();
        int wpref = 0;
        for (int w = 0; w < wid; ++w) wpref += wsum[w];
        int excl = wpref + acc - v;
        if (tid == b) { sbase = excl; scnt = v; }
    }
    __syncthreads();
    const int cntb = scnt;
    const int base = sbase + b * BSLACK;     // padded slack per bucket
    const int2* sp = bstage + (size_t)b * BCAP;

    if (tid < 128) cnt128[tid] = 0;
    __syncthreads();
    for (int i = tid; i < cntb; i += 512)
        atomicAdd(&cnt128[sp[i].y & 127], 1);
    __syncthreads();

    // scan 128 per-node PADDED counts (first 2 waves carry data)
    int v = (tid < 128) ? cnt128[tid] : 0;
    int pcv = (v + 3) & ~3;
    int acc = pcv;
#pragma unroll
    for (int off = 1; off < 64; off <<= 1) {
        int t = __shfl_up(acc, off, 64);
        if (lane >= off) acc += t;
    }
    if (lane == 63) wsum[wid] = acc;
    __syncthreads();
    int wpref = 0;
    for (int w = 0; w < wid; ++w) wpref += wsum[w];
    int excl = wpref + acc - pcv;
    if (tid < 128) {
        int node = node0 + tid;
        if (node < n) {
            row_start[node] = base + excl;
            row_end[node]   = base + excl + pcv;
        }
        curs[tid] = excl;
        // zero-fill the <=3 pad slots so they read as (src 0, weight +0.0)
        for (int k = v; k < pcv; ++k) perm4[base + excl + k] = 0u;
    }
    __syncthreads();

    for (int i = tid; i < cntb; i += 512) {
        int2 p = sp[i];
        int pos = atomicAdd(&curs[p.y & 127], 1);
        perm4[base + pos] = (unsigned int)p.x;
    }
}

// ---------------------------------------------------------------------------
// Fused layer v13 = v9 with full occupancy: __launch_bounds__(256, 8) lets
// 8 blocks/CU (32 waves/CU, was 24) reside — VGPR=36 and LDS=4.25KB permit it,
// and the 3125-block grid can feed it. Everything else identical to round 5.
#define ACCQ(p, v) do { \
    float w_ = __half2float(__ushort_as_half((unsigned short)((p) >> 16))); \
    floatx2 W_ = (floatx2){w_, w_}; \
    floatx2 f0_ = __builtin_amdgcn_cvt_pk_f32_fp8((v).x, false); \
    floatx2 f1_ = __builtin_amdgcn_cvt_pk_f32_fp8((v).x, true);  \
    floatx2 f2_ = __builtin_amdgcn_cvt_pk_f32_fp8((v).y, false); \
    floatx2 f3_ = __builtin_amdgcn_cvt_pk_f32_fp8((v).y, true);  \
    ac[0] += W_ * f0_; ac[1] += W_ * f1_; \
    ac[2] += W_ * f2_; ac[3] += W_ * f3_; \
} while (0)

__global__ __launch_bounds__(256, 8)
void fused_layer(const unsigned short* __restrict__ h, const unsigned char* __restrict__ h8,
                 const int* __restrict__ row_start, const int* __restrict__ row_end,
                 const unsigned int* __restrict__ perm4, const unsigned short* __restrict__ Wp,
                 const float* __restrict__ bias, float* __restrict__ outF,
                 unsigned short* __restrict__ outB, unsigned char* __restrict__ outB8,
                 int relu) {
    __shared__ unsigned short Gs[16 * LDSROW];   // 4.25 KB
    const int tid  = threadIdx.x;
    const int lane = tid & 63;
    const int wid  = tid >> 6;
    const int g  = lane >> 4;      // node owner (phase1) / k-offset quad (phase2)
    const int sl = lane & 15;      // col-chunk (phase1) / A-row (phase2)
    const int rowT = blockIdx.x * 16;
    const int nodeBase = rowT + wid * 4;

    // beg/end for the wave's 4 nodes: lanes 0-3 load row_start, 4-7 row_end
    int rs = 0;
    {
        int idx = nodeBase + (lane & 3);
        if (lane < 4)      rs = row_start[idx];
        else if (lane < 8) rs = row_end[idx];
    }
    const int beg = __shfl(rs, g, 64);
    const int end = __shfl(rs, g + 4, 64);

    // ---- phase 1: group g aggregates node nodeBase+g, dims [8sl, 8sl+8) ----
    floatx2 ac[4];
#pragma unroll
    for (int k = 0; k < 4; ++k) ac[k] = (floatx2){0.f, 0.f};
    const unsigned char* hp8 = h8 + sl * 8;
    const bool any = beg < end;
    uint4 P = {};
    uint2 v0 = {}, v1 = {}, v2 = {}, v3 = {};
    int t = beg;
    if (any) {
        P  = *(const uint4*)(perm4 + t);     // 16B broadcast: all 16 lanes same addr
        v0 = *(const uint2*)(hp8 + (size_t)(P.x & 0xFFFFu) * DIM);
        v1 = *(const uint2*)(hp8 + (size_t)(P.y & 0xFFFFu) * DIM);
        v2 = *(const uint2*)(hp8 + (size_t)(P.z & 0xFFFFu) * DIM);
        v3 = *(const uint2*)(hp8 + (size_t)(P.w & 0xFFFFu) * DIM);
    }
    for (; t + 4 < end; t += 4) {
        uint4 Pn = *(const uint4*)(perm4 + t + 4);
        uint2 w0 = *(const uint2*)(hp8 + (size_t)(Pn.x & 0xFFFFu) * DIM);
        uint2 w1 = *(const uint2*)(hp8 + (size_t)(Pn.y & 0xFFFFu) * DIM);
        uint2 w2 = *(const uint2*)(hp8 + (size_t)(Pn.z & 0xFFFFu) * DIM);
        uint2 w3 = *(const uint2*)(hp8 + (size_t)(Pn.w & 0xFFFFu) * DIM);
        ACCQ(P.x, v0); ACCQ(P.y, v1); ACCQ(P.z, v2); ACCQ(P.w, v3);
        P = Pn;
        v0 = w0; v1 = w1; v2 = w2; v3 = w3;
    }
    if (any) { ACCQ(P.x, v0); ACCQ(P.y, v1); ACCQ(P.z, v2); ACCQ(P.w, v3); }

    // group g's 16 lanes hold the full 128-dim aggregate of its node
    {
        uint4 r;
        r.x = (unsigned int)f2bf(ac[0].x) | ((unsigned int)f2bf(ac[0].y) << 16);
        r.y = (unsigned int)f2bf(ac[1].x) | ((unsigned int)f2bf(ac[1].y) << 16);
        r.z = (unsigned int)f2bf(ac[2].x) | ((unsigned int)f2bf(ac[2].y) << 16);
        r.w = (unsigned int)f2bf(ac[3].x) | ((unsigned int)f2bf(ac[3].y) << 16);
        *(uint4*)(&Gs[(wid * 4 + g) * LDSROW + sl * 8]) = r;
    }

    // ---- phase 1.5: root-GEMM half (h rows, no LDS dependency) ----
    floatx4 acc2[2];
#pragma unroll
    for (int ct = 0; ct < 2; ++ct) acc2[ct] = (floatx4){0.f, 0.f, 0.f, 0.f};
    const int rr = rowT + sl;          // grid exact: always < N
    const int ko = g * 8;
#pragma unroll
    for (int t2 = 4; t2 < 8; ++t2) {
        shortx8 a = *(const shortx8*)(h + (size_t)rr * DIM + (t2 - 4) * 32 + ko);
        const unsigned short* wp = Wp + (size_t)t2 * 4096 + (wid * 2) * 512 + lane * 8;
#pragma unroll
        for (int ct = 0; ct < 2; ++ct) {
            shortx8 b = *(const shortx8*)(wp + ct * 512);
            acc2[ct] = __builtin_amdgcn_mfma_f32_16x16x32_bf16(a, b, acc2[ct], 0, 0, 0);
        }
    }

    __syncthreads();   // waves now read rows written by other waves

    // ---- phase 2: aggregate-GEMM half from LDS ----
#pragma unroll
    for (int t2 = 0; t2 < 4; ++t2) {
        shortx8 a = *(const shortx8*)(&Gs[sl * LDSROW + t2 * 32 + ko]);
        const unsigned short* wp = Wp + (size_t)t2 * 4096 + (wid * 2) * 512 + lane * 8;
#pragma unroll
        for (int ct = 0; ct < 2; ++ct) {
            shortx8 b = *(const shortx8*)(wp + ct * 512);
            acc2[ct] = __builtin_amdgcn_mfma_f32_16x16x32_bf16(a, b, acc2[ct], 0, 0, 0);
        }
    }

#pragma unroll
    for (int ct = 0; ct < 2; ++ct) {
        int col = wid * 32 + ct * 16 + sl;
        float bv = bias[col];
#pragma unroll
        for (int i = 0; i < 4; ++i) {
            int row = rowT + g * 4 + i;
            float v = acc2[ct][i] + bv;
            if (relu) v = fmaxf(v, 0.f);
            if (outF) {
                outF[(size_t)row * DIM + col] = v;
            } else {
                outB[(size_t)row * DIM + col]  = f2bf(v);
                outB8[(size_t)row * DIM + col] = f2fp8(v);
            }
        }
    }
}

extern "C" void kernel_launch(void* const* d_in, const int* in_sizes, int n_in,
                              void* d_out, int out_size, void* d_ws, size_t ws_size,
                              hipStream_t stream) {
    const int N = N_NODES, E = N_EDGES;

    const float* x   = (const float*)d_in[0];
    const int*   ei  = (const int*)d_in[1];
    const float* ea  = (const float*)d_in[2];
    const float* wr0 = (const float*)d_in[3];
    const float* br0 = (const float*)d_in[4];
    const float* wt0 = (const float*)d_in[5];
    const float* wr1 = (const float*)d_in[6];
    const float* br1 = (const float*)d_in[7];
    const float* wt1 = (const float*)d_in[8];
    const float* wr2 = (const float*)d_in[9];
    const float* br2 = (const float*)d_in[10];
    const float* wt2 = (const float*)d_in[11];
    const int* srcI = ei;
    const int* dstI = ei + E;
    float* out = (float*)d_out;

    // workspace layout — every array before the fp8 tables has a size that is
    // a multiple of 128 B, so X8/H81/H82 rows are 128B-aligned (2 lines/row),
    // and perm4 is 128B-aligned (dwordx4 quad loads).
    int2* bstage = (int2*)d_ws;                              // 391*2816*8 = 8,808,448 B
    unsigned short* X  = (unsigned short*)(bstage + (size_t)NBUCK * BCAP);  // 12.8 MB
    unsigned short* H1 = X + (size_t)N * DIM;                // 12.8 MB
    unsigned short* H2 = H1 + (size_t)N * DIM;               // 12.8 MB
    unsigned short* Wp = H2 + (size_t)N * DIM;               // 196,608 B
    unsigned char* X8  = (unsigned char*)(Wp + 3 * 32768);   // 6.4 MB (128B-aligned)
    unsigned char* H81 = X8 + (size_t)N * DIM;               // 6.4 MB
    unsigned char* H82 = H81 + (size_t)N * DIM;              // 6.4 MB
    unsigned int* perm4 = (unsigned int*)(H82 + (size_t)N * DIM);  // E + NBUCK*BSLACK (<1M) u32
    int* bcursor = (int*)(perm4 + 1000000);                  // NBUCK i32
    int* rowst   = bcursor + NBUCK;                          // N i32
    int* rowend  = rowst + N_NODES;                          // N i32

    // prep (cvt + zero + pack) and CSR build via binned counting sort
    prep_kernel<<<CVT_BLOCKS + 1 + 384, 256, 0, stream>>>(x, X, X8, wr0, wt0, wr1, wt1, wr2, wt2, Wp, bcursor);
    partition_kernel<<<(E + CHUNK - 1) / CHUNK, 1024, 0, stream>>>(srcI, dstI, ea, bcursor, bstage, E);
    bucket_fill_kernel<<<NBUCK, 512, 0, stream>>>(bstage, bcursor, rowst, rowend, perm4, N);

    const int fusedGrid = N / 16;            // 3125 blocks, 16 rows each (exact)

    // ping-pong h buffers: gathers read prev layer's fp8 copy
    fused_layer<<<fusedGrid, 256, 0, stream>>>(X,  X8,  rowst, rowend, perm4, Wp,         br0, nullptr, H1, H81, 1);
    fused_layer<<<fusedGrid, 256, 0, stream>>>(H1, H81, rowst, rowend, perm4, Wp + 32768, br1, nullptr, H2, H82, 1);
    fused_layer<<<fusedGrid, 256, 0, stream>>>(H2, H82, rowst, rowend, perm4, Wp + 65536, br2, out, nullptr, nullptr, 0);
}